// Round 9
// baseline (100.370 us; speedup 1.0000x reference)
//
#include <hip/hip_runtime.h>

#define NT 1024

__device__ __forceinline__ int refl(int i, int n) {
    i = (i < 0) ? (-i - 1) : i;
    i = (i >= n) ? (2 * n - 1 - i) : i;
    return i;
}

// round-to-nearest-even bf16 pack of (lo -> low16, hi -> high16)
__device__ __forceinline__ unsigned bpack(float lo, float hi) {
    union { float f; unsigned u; } a, b;
    a.f = lo; b.f = hi;
    const unsigned ua = (a.u + 0x7FFFu + ((a.u >> 16) & 1u)) >> 16;
    const unsigned ub = (b.u + 0x7FFFu + ((b.u >> 16) & 1u)) & 0xFFFF0000u;
    return ua | ub;
}
__device__ __forceinline__ float b_lo(unsigned u) {
    union { unsigned u; float f; } x; x.u = u << 16; return x.f;
}
__device__ __forceinline__ float b_hi(unsigned u) {
    union { unsigned u; float f; } x; x.u = u & 0xFFFF0000u; return x.f;
}

__device__ __constant__ const float LOF[8] = {
    -0.010597401784997278f,  0.032883011666982945f,
     0.030841381835986965f, -0.18703481171888114f,
    -0.02798376941698385f,   0.6308807679295904f,
     0.7148465705525415f,    0.23037781330885523f };
__device__ __constant__ const float HIF[8] = {
    -0.23037781330885523f,   0.7148465705525415f,
    -0.6308807679295904f,   -0.02798376941698385f,
     0.18703481171888114f,   0.030841381835986965f,
    -0.032883011666982945f, -0.010597401784997278f };

// Phase-A work item: one halo row tr (0..133), one 8-out-col group g (0..7).
// Loads 24 input floats (6 aligned float4), computes 8 (lo,hi) pairs,
// writes 2 uint4 to LDS row tr (pitch 68 dwords).
template<bool FAST>
__device__ __forceinline__ void itemA(int item, const float* __restrict__ Ain,
                                      int n, int ldin, int rb, int cw0,
                                      unsigned* __restrict__ s)
{
    const int tr = item >> 3, g = item & 7;
    const int cw = cw0 + 16 * g;
    float v[24];
    if (FAST) {
        const float* p = Ain + (rb + tr) * ldin + cw;
        #pragma unroll
        for (int j = 0; j < 6; ++j) {
            const float4 t4 = *(const float4*)(p + 4 * j);
            v[4*j] = t4.x; v[4*j+1] = t4.y; v[4*j+2] = t4.z; v[4*j+3] = t4.w;
        }
    } else {
        const float* row = Ain + refl(rb + tr, n) * ldin;
        #pragma unroll
        for (int u = 0; u < 24; ++u) v[u] = row[refl(cw + u, n)];
    }
    unsigned w[8];
    #pragma unroll
    for (int d = 0; d < 8; ++d) {
        float lo = 0.f, hi = 0.f;
        #pragma unroll
        for (int k = 0; k < 8; ++k) {
            const float x = v[2 * d + 9 - k];
            lo += LOF[k] * x;
            hi += HIF[k] * x;
        }
        w[d] = bpack(lo, hi);
    }
    unsigned* dst = &s[tr * 68 + 8 * g];
    *(uint4*)(dst)     = make_uint4(w[0], w[1], w[2], w[3]);
    *(uint4*)(dst + 4) = make_uint4(w[4], w[5], w[6], w[7]);
}

// Phase-B work item: 2 adjacent cols (c2), 2 output rows (pr).
// 10 ds_read_b64, 64 FMA, up to 16 dword stores.
__device__ __forceinline__ void itemB(int c2, int pr, const unsigned* __restrict__ s,
                                      int r0, int c0, int m,
                                      float* __restrict__ oA, int ldA, int oaB,
                                      float* __restrict__ oH, float* __restrict__ oV,
                                      float* __restrict__ oD, int obB)
{
    uint2 u[10];
    #pragma unroll
    for (int j = 0; j < 10; ++j)
        u[j] = *(const uint2*)&s[(4 * pr + j) * 68 + 2 * c2];
    const int gr = r0 + 2 * pr;
    #pragma unroll
    for (int col = 0; col < 2; ++col) {
        const int gc = c0 + 2 * c2 + col;
        if (gc >= m) continue;
        float lov[10], hiv[10];
        #pragma unroll
        for (int j = 0; j < 10; ++j) {
            const unsigned uu = col ? u[j].y : u[j].x;
            lov[j] = b_lo(uu); hiv[j] = b_hi(uu);
        }
        float A0 = 0.f, H0 = 0.f, V0 = 0.f, D0 = 0.f;
        float A1 = 0.f, H1 = 0.f, V1 = 0.f, D1 = 0.f;
        #pragma unroll
        for (int k = 0; k < 8; ++k) {
            const float l0 = lov[7 - k], h0 = hiv[7 - k];
            const float l1 = lov[9 - k], h1 = hiv[9 - k];
            A0 += LOF[k] * l0;  H0 += HIF[k] * l0;
            V0 += LOF[k] * h0;  D0 += HIF[k] * h0;
            A1 += LOF[k] * l1;  H1 += HIF[k] * l1;
            V1 += LOF[k] * h1;  D1 += HIF[k] * h1;
        }
        const int od = obB + gr * m + gc;
        if (gr < m) {
            oA[oaB + gr * ldA + gc] = A0;
            oH[od] = H0; oV[od] = V0; oD[od] = D0;
        }
        if (gr + 1 < m) {
            oA[oaB + (gr + 1) * ldA + gc] = A1;
            oH[od + m] = H1; oV[od + m] = V1; oD[od + m] = D1;
        }
    }
}

// One fused 2D DWT level, 64x64 output tile per block, NT=1024 (2 blocks/CU).
// out[i] = sum_k f[k] * x[refl(2i+1-k)] on both axes.
// LDS: bf16-packed horizontal (lo,hi), 134 rows x 68 dword cols (36.4 KB).
__global__ __launch_bounds__(NT, 8)
void dwt2_fused(const float* __restrict__ in, int n, int ldin, int inb,
                int m, int nty, int ntx,
                float* __restrict__ oA, int ldA, int Ab,
                float* __restrict__ oH, float* __restrict__ oV,
                float* __restrict__ oD)
{
    __shared__ unsigned s[134 * 68];   // 36448 B

    // bijective XCD-chunked remap, y-fastest tile order (proven R5)
    const int G = gridDim.x;
    const int q = G >> 3, rm = G & 7;
    const int xcd = blockIdx.x & 7, pos = blockIdx.x >> 3;
    const int i = xcd * q + (xcd < rm ? xcd : rm) + pos;
    const int ty = i % nty;
    const int t2 = i / nty;
    const int tx = t2 % ntx;
    const int b  = t2 / ntx;

    const int tid = threadIdx.x;
    const int c0 = tx * 64, r0 = ty * 64;
    const float* Ain = in + b * inb;

    const int rb  = 2 * r0 - 6;    // LDS row t <-> input row rb+t (t 0..133)
    const int cw0 = 2 * c0 - 8;    // group g window: cols cw0+16g .. +23

    const bool interior = (rb >= 0) && (rb + 133 < n) &&
                          (cw0 >= 0) && (2 * c0 + 127 < n);

    // ---- Phase A: 1072 items = 134 rows x 8 groups ----
    if (interior) {
        itemA<true>(tid, Ain, n, ldin, rb, cw0, s);
        if (tid < 48) itemA<true>(tid + 1024, Ain, n, ldin, rb, cw0, s);
    } else {
        itemA<false>(tid, Ain, n, ldin, rb, cw0, s);
        if (tid < 48) itemA<false>(tid + 1024, Ain, n, ldin, rb, cw0, s);
    }
    __syncthreads();

    // ---- Phase B: 1024 items = 32 col-pairs x 32 row-pairs, 1/thread ----
    const int c2 = tid & 31, pr = tid >> 5;
    itemB(c2, pr, s, r0, c0, m, oA, ldA, b * Ab, oH, oV, oD, b * m * m);
}

extern "C" void kernel_launch(void* const* d_in, const int* in_sizes, int n_in,
                              void* d_out, int out_size, void* d_ws, size_t ws_size,
                              hipStream_t stream) {
    const float* x = (const float*)d_in[0];
    float* out = (float*)d_out;
    float* ws  = (float*)d_ws;

    const int B = 16;
    const int n1 = 1024, m1 = 515;
    const int n2 = 515,  m2 = 261;
    const int n3 = 261,  m3 = 134;

    // padded cA intermediates (rows 16B-aligned)
    const int ld1 = 516, b1 = m1 * ld1;
    const int ld2 = 264, b2 = m2 * ld2;
    float* a1 = ws;
    float* a2 = ws + (size_t)b1 * B;

    const size_t sz1 = (size_t)B * m1 * m1;
    const size_t sz2 = (size_t)B * m2 * m2;
    const size_t sz3 = (size_t)B * m3 * m3;

    // d_out: a3, lh3, hl3, hh3, lh2, hl2, hh2, lh1, hl1, hh1
    float* a3  = out;
    float* lh3 = a3  + sz3;
    float* hl3 = lh3 + sz3;
    float* hh3 = hl3 + sz3;
    float* lh2 = hh3 + sz3;
    float* hl2 = lh2 + sz2;
    float* hh2 = hl2 + sz2;
    float* lh1 = hh2 + sz2;
    float* hl1 = lh1 + sz1;
    float* hh1 = hl1 + sz1;

    const int t1 = (m1 + 63) / 64;   // 9
    const int t2_ = (m2 + 63) / 64;  // 5
    const int t3 = (m3 + 63) / 64;   // 3

    dim3 blk(NT);
    dim3 g1(t1 * t1 * B, 1, 1);      // 1296
    dim3 g2(t2_ * t2_ * B, 1, 1);    // 400
    dim3 g3(t3 * t3 * B, 1, 1);      // 144

    dwt2_fused<<<g1, blk, 0, stream>>>(x,  n1, n1, n1 * n1,
                                       m1, t1, t1, a1, ld1, b1, lh1, hl1, hh1);
    dwt2_fused<<<g2, blk, 0, stream>>>(a1, n2, ld1, b1,
                                       m2, t2_, t2_, a2, ld2, b2, lh2, hl2, hh2);
    dwt2_fused<<<g3, blk, 0, stream>>>(a2, n3, ld2, b2,
                                       m3, t3, t3, out, m3, m3 * m3, lh3, hl3, hh3);
}

// Round 10
// 70.381 us; speedup vs baseline: 1.4261x; 1.4261x over previous
//
#include <hip/hip_runtime.h>

#define NT 256
#define NTF 512   // fused kernel (levels 2-3), proven R8

__device__ __forceinline__ int refl(int i, int n) {
    i = (i < 0) ? (-i - 1) : i;
    i = (i >= n) ? (2 * n - 1 - i) : i;
    return i;
}

// RNE bf16 pack: lo -> low16, hi -> high16
__device__ __forceinline__ unsigned bpack(float lo, float hi) {
    union { float f; unsigned u; } a, b;
    a.f = lo; b.f = hi;
    const unsigned ua = (a.u + 0x7FFFu + ((a.u >> 16) & 1u)) >> 16;
    const unsigned ub = (b.u + 0x7FFFu + ((b.u >> 16) & 1u)) & 0xFFFF0000u;
    return ua | ub;
}
__device__ __forceinline__ float b_lo(unsigned u) {
    union { unsigned u; float f; } x; x.u = u << 16; return x.f;
}
__device__ __forceinline__ float b_hi(unsigned u) {
    union { unsigned u; float f; } x; x.u = u & 0xFFFF0000u; return x.f;
}

__device__ __constant__ const float LOF[8] = {
    -0.010597401784997278f,  0.032883011666982945f,
     0.030841381835986965f, -0.18703481171888114f,
    -0.02798376941698385f,   0.6308807679295904f,
     0.7148465705525415f,    0.23037781330885523f };
__device__ __constant__ const float HIF[8] = {
    -0.23037781330885523f,   0.7148465705525415f,
    -0.6308807679295904f,   -0.02798376941698385f,
     0.18703481171888114f,   0.030841381835986965f,
    -0.032883011666982945f, -0.010597401784997278f };

// -------- Horizontal streaming pass --------
// out[row][c] (packed lo|hi) = h-conv of in[row][*]; c in groups of 8.
// Thread = 1 row x 8 out cols. Interior threads [0,Tint): g in [1, ng-2]
// (always in-bounds). Edge threads after: g in {0, ng-1}, refl gather.
__device__ __forceinline__ void hconv8(const float v[24], unsigned w[8]) {
    #pragma unroll
    for (int d = 0; d < 8; ++d) {
        float lo = 0.f, hi = 0.f;
        #pragma unroll
        for (int k = 0; k < 8; ++k) {
            const float x = v[2 * d + 9 - k];
            lo += LOF[k] * x;
            hi += HIF[k] * x;
        }
        w[d] = bpack(lo, hi);
    }
}

__global__ __launch_bounds__(NT)
void dwt_h(const float* __restrict__ in, int n, int ldin, int inb,
           unsigned* __restrict__ op, int ldo, int ob,
           int rows, int ng, int Tint, int total)
{
    const int t = blockIdx.x * NT + threadIdx.x;
    if (t >= total) return;

    int g, row, b;
    float v[24];
    if (t < Tint) {
        const int ngi = ng - 2;
        g = 1 + t % ngi;
        const int rr = t / ngi;
        row = rr % rows;
        b = rr / rows;
        const float* base = in + b * inb + row * ldin + (16 * g - 8);
        #pragma unroll
        for (int j = 0; j < 6; ++j) {
            const float4 t4 = *(const float4*)(base + 4 * j);
            v[4*j] = t4.x; v[4*j+1] = t4.y; v[4*j+2] = t4.z; v[4*j+3] = t4.w;
        }
    } else {
        const int e = t - Tint;
        g = (e & 1) ? (ng - 1) : 0;
        const int rr = e >> 1;
        row = rr % rows;
        b = rr / rows;
        const float* base = in + b * inb + row * ldin;
        const int cb = 16 * g - 8;
        #pragma unroll
        for (int u = 0; u < 24; ++u) v[u] = base[refl(cb + u, n)];
    }

    unsigned w[8];
    hconv8(v, w);
    unsigned* o = op + b * ob + row * ldo + 8 * g;
    *(uint4*)(o) = make_uint4(w[0], w[1], w[2], w[3]);
    if (8 * g + 7 < ldo)
        *(uint4*)(o + 4) = make_uint4(w[4], w[5], w[6], w[7]);
}

// -------- Vertical streaming pass --------
// Thread = 1 col x 2 out rows (r2). Loads 10 packed dwords (rows 4r2-6..4r2+3),
// writes A + 3 detail bands, all lane-contiguous scalar dwords.
// Interior threads: r2 = 2 + rf (rows in-bounds). Edge tail: refl rows.
__global__ __launch_bounds__(NT)
void dwt_v(const unsigned* __restrict__ inp, int ldi, int ib, int n,
           int m, int wcols,
           float* __restrict__ oA, int ldA, int Ab,
           float* __restrict__ oH, float* __restrict__ oVb,
           float* __restrict__ oD, int db,
           int nfast, int Tint, int total)
{
    const int t = blockIdx.x * NT + threadIdx.x;
    if (t >= total) return;

    int c, r2, b;
    unsigned u[10];
    if (t < Tint) {
        c = t % wcols;
        const int rr = t / wcols;
        r2 = 2 + rr % nfast;
        b = rr / nfast;
        const unsigned* colp = inp + b * ib + c + (4 * r2 - 6) * ldi;
        #pragma unroll
        for (int j = 0; j < 10; ++j) u[j] = colp[j * ldi];
    } else {
        const int e = t - Tint;
        c = e % wcols;
        const int rr = e / wcols;
        const int nsl = rr; // which-index packed with batch below
        // decompose: which = nsl % nslow, b = nsl / nslow; nslow derivable:
        // pass via Tint/total structure instead: recompute
        // (we pass nslow implicitly: total-Tint = wcols*nslow*nb)
        // To keep it simple we pass nslow in ldA? No: compute from edge list:
        // which < 2 -> r2 = which ; else r2 = nfast + which
        // nslow is small; we recover it from n: nrp = (m+1)/2? m rows: nrp=ceil(m/2)
        const int nrp = (m + 1) / 2;
        const int nslow = nrp - nfast - 2 + 2; // rows 0,1 + tail rows
        const int which = nsl % nslow;
        b = nsl / nslow;
        r2 = (which < 2) ? which : (nfast + which);
        const unsigned* colp = inp + b * ib + c;
        const int rbase = 4 * r2 - 6;
        #pragma unroll
        for (int j = 0; j < 10; ++j) u[j] = colp[refl(rbase + j, n) * ldi];
    }

    float lov[10], hiv[10];
    #pragma unroll
    for (int j = 0; j < 10; ++j) { lov[j] = b_lo(u[j]); hiv[j] = b_hi(u[j]); }

    float A0 = 0.f, H0 = 0.f, V0 = 0.f, D0 = 0.f;
    float A1 = 0.f, H1 = 0.f, V1 = 0.f, D1 = 0.f;
    #pragma unroll
    for (int k = 0; k < 8; ++k) {
        const float l0 = lov[7 - k], h0 = hiv[7 - k];
        const float l1 = lov[9 - k], h1 = hiv[9 - k];
        A0 += LOF[k] * l0;  H0 += HIF[k] * l0;
        V0 += LOF[k] * h0;  D0 += HIF[k] * h0;
        A1 += LOF[k] * l1;  H1 += HIF[k] * l1;
        V1 += LOF[k] * h1;  D1 += HIF[k] * h1;
    }
    const int gr = 2 * r2;
    const int od = b * db + gr * wcols + c;
    oA[b * Ab + gr * ldA + c] = A0;
    oH[od] = H0; oVb[od] = V0; oD[od] = D0;
    if (gr + 1 < m) {
        oA[b * Ab + (gr + 1) * ldA + c] = A1;
        oH[od + wcols] = H1; oVb[od + wcols] = V1; oD[od + wcols] = D1;
    }
}

// -------- Fused kernel (R8, proven) for levels 2-3 --------
__global__ __launch_bounds__(NTF, 8)
void dwt2_fused(const float* __restrict__ in, int n, int ldin, int inb,
                int m, int nty, int ntx,
                float* __restrict__ oA, int ldA, int Ab,
                float* __restrict__ oH, float* __restrict__ oV,
                float* __restrict__ oD)
{
    __shared__ unsigned s[70 * 36];

    const int G = gridDim.x;
    const int q = G >> 3, rm = G & 7;
    const int xcd = blockIdx.x & 7, pos = blockIdx.x >> 3;
    const int i = xcd * q + (xcd < rm ? xcd : rm) + pos;
    const int ty = i % nty;
    const int t2 = i / nty;
    const int tx = t2 % ntx;
    const int b  = t2 / ntx;

    const int tid = threadIdx.x;
    const int c0 = tx * 32, r0 = ty * 32;
    const float* Ain = in + b * inb;

    const int rb  = 2 * r0 - 6;
    const int cw0 = 2 * c0 - 8;
    const bool interior = (rb >= 0) && (rb + 69 < n) && (cw0 >= 0) && (cw0 + 71 < n);

    const int tr0 = tid >> 3, g0 = tid & 7;
    const bool has2 = (tid < 48);
    const int tr1 = 64 + (tid >> 3), g1 = tid & 7;

    float v0[16], v1[16];
    if (interior) {
        const float* p0 = Ain + (rb + tr0) * ldin + (cw0 + 8 * g0);
        const float4 a0 = ((const float4*)p0)[0];
        const float4 a1 = ((const float4*)p0)[1];
        const float4 a2 = ((const float4*)p0)[2];
        const float4 a3 = ((const float4*)p0)[3];
        v0[0]=a0.x; v0[1]=a0.y; v0[2]=a0.z; v0[3]=a0.w;
        v0[4]=a1.x; v0[5]=a1.y; v0[6]=a1.z; v0[7]=a1.w;
        v0[8]=a2.x; v0[9]=a2.y; v0[10]=a2.z; v0[11]=a2.w;
        v0[12]=a3.x; v0[13]=a3.y; v0[14]=a3.z; v0[15]=a3.w;
        if (has2) {
            const float* p1 = Ain + (rb + tr1) * ldin + (cw0 + 8 * g1);
            const float4 b0 = ((const float4*)p1)[0];
            const float4 b1 = ((const float4*)p1)[1];
            const float4 b2 = ((const float4*)p1)[2];
            const float4 b3 = ((const float4*)p1)[3];
            v1[0]=b0.x; v1[1]=b0.y; v1[2]=b0.z; v1[3]=b0.w;
            v1[4]=b1.x; v1[5]=b1.y; v1[6]=b1.z; v1[7]=b1.w;
            v1[8]=b2.x; v1[9]=b2.y; v1[10]=b2.z; v1[11]=b2.w;
            v1[12]=b3.x; v1[13]=b3.y; v1[14]=b3.z; v1[15]=b3.w;
        }
    } else {
        const float* row0 = Ain + refl(rb + tr0, n) * ldin;
        const int cb0 = cw0 + 8 * g0;
        #pragma unroll
        for (int u = 0; u < 16; ++u) v0[u] = row0[refl(cb0 + u, n)];
        if (has2) {
            const float* row1 = Ain + refl(rb + tr1, n) * ldin;
            const int cb1 = cw0 + 8 * g1;
            #pragma unroll
            for (int u = 0; u < 16; ++u) v1[u] = row1[refl(cb1 + u, n)];
        }
    }

    {
        unsigned w[4];
        #pragma unroll
        for (int d = 0; d < 4; ++d) {
            float lo = 0.f, hi = 0.f;
            #pragma unroll
            for (int k = 0; k < 8; ++k) {
                const float x = v0[2 * d + 9 - k];
                lo += LOF[k] * x;
                hi += HIF[k] * x;
            }
            w[d] = bpack(lo, hi);
        }
        *(uint4*)&s[tr0 * 36 + 4 * g0] = make_uint4(w[0], w[1], w[2], w[3]);
    }
    if (has2) {
        unsigned w[4];
        #pragma unroll
        for (int d = 0; d < 4; ++d) {
            float lo = 0.f, hi = 0.f;
            #pragma unroll
            for (int k = 0; k < 8; ++k) {
                const float x = v1[2 * d + 9 - k];
                lo += LOF[k] * x;
                hi += HIF[k] * x;
            }
            w[d] = bpack(lo, hi);
        }
        *(uint4*)&s[tr1 * 36 + 4 * g1] = make_uint4(w[0], w[1], w[2], w[3]);
    }
    __syncthreads();

    const int c = tid & 31, pr = tid >> 5;
    float lov[10], hiv[10];
    #pragma unroll
    for (int j = 0; j < 10; ++j) {
        const unsigned u = s[(4 * pr + j) * 36 + c];
        lov[j] = b_lo(u); hiv[j] = b_hi(u);
    }
    float A0 = 0.f, H0 = 0.f, V0 = 0.f, D0 = 0.f;
    float A1 = 0.f, H1 = 0.f, V1 = 0.f, D1 = 0.f;
    #pragma unroll
    for (int k = 0; k < 8; ++k) {
        const float l0 = lov[7 - k], h0 = hiv[7 - k];
        const float l1 = lov[9 - k], h1 = hiv[9 - k];
        A0 += LOF[k] * l0;  H0 += HIF[k] * l0;
        V0 += LOF[k] * h0;  D0 += HIF[k] * h0;
        A1 += LOF[k] * l1;  H1 += HIF[k] * l1;
        V1 += LOF[k] * h1;  D1 += HIF[k] * h1;
    }
    const int gr = r0 + 2 * pr, gc = c0 + c;
    if (gc < m) {
        const int ob = b * (m * m);
        const int od = ob + gr * m + gc;
        if (gr < m) {
            oA[b * Ab + gr * ldA + gc] = A0;
            oH[od] = H0; oV[od] = V0; oD[od] = D0;
        }
        if (gr + 1 < m) {
            oA[b * Ab + (gr + 1) * ldA + gc] = A1;
            oH[od + m] = H1; oV[od + m] = V1; oD[od + m] = D1;
        }
    }
}

extern "C" void kernel_launch(void* const* d_in, const int* in_sizes, int n_in,
                              void* d_out, int out_size, void* d_ws, size_t ws_size,
                              hipStream_t stream) {
    const float* x = (const float*)d_in[0];
    float* out = (float*)d_out;

    const int B = 16;
    const int n1 = 1024, m1 = 515;
    const int n2 = 515,  m2 = 261;
    const int n3 = 261,  m3 = 134;

    const int ld1 = 516;                 // inter1 & a1 pitch (dwords/floats)
    const int ld2 = 264;                 // a2 pitch
    const size_t sz1 = (size_t)B * m1 * m1;
    const size_t sz2 = (size_t)B * m2 * m2;
    const size_t sz3 = (size_t)B * m3 * m3;

    // d_out: a3, lh3, hl3, hh3, lh2, hl2, hh2, lh1, hl1, hh1
    float* a3  = out;
    float* lh3 = a3  + sz3;
    float* hl3 = lh3 + sz3;
    float* hh3 = hl3 + sz3;
    float* lh2 = hh3 + sz3;
    float* hl2 = lh2 + sz2;
    float* hh2 = hl2 + sz2;
    float* lh1 = hh2 + sz2;
    float* hl1 = lh1 + sz1;
    float* hh1 = lh1 + 2 * sz1;

    // ws ladder: per-batch dwords = inter1 (516*1024) + a1 (516*515)
    const size_t perb = ((size_t)ld1 * n1 + (size_t)ld1 * m1) * 4;   // bytes
    int nb = B;
    while (nb > 1 && (size_t)nb * perb > ws_size) nb >>= 1;

    unsigned* X = (unsigned*)d_ws;                       // inter1 / a2 region
    float*    Y = (float*)((unsigned*)d_ws + (size_t)ld1 * n1 * nb); // a1

    // level-1 H geometry
    const int ng1 = 65;                                  // ceil(515/8)
    const int h1_Tint  = n1 * (ng1 - 2) * nb;
    const int h1_total = h1_Tint + n1 * 2 * nb;
    // level-1 V geometry
    const int nrp1 = (m1 + 1) / 2;                       // 258
    const int nfast1 = (n1 - 4) / 4 - 1;                 // 254
    const int nslow1 = nrp1 - nfast1 - 2 + 2;            // 4
    const int v1_Tint  = m1 * nfast1 * nb;
    const int v1_total = v1_Tint + m1 * nslow1 * nb;

    const int t2_ = (m2 + 31) / 32;  // 9
    const int t3  = (m3 + 31) / 32;  // 5

    const int a1b = ld1 * m1;        // a1 per-batch stride
    const int a2b = ld2 * m2;        // a2 per-batch stride (a2 lives in X)

    for (int g0 = 0; g0 < B; g0 += nb) {
        const float* xin = x + (size_t)g0 * n1 * n1;

        // H1: x -> X (packed), rows n1, pitch ld1
        dwt_h<<<dim3((h1_total + NT - 1) / NT), dim3(NT), 0, stream>>>(
            xin, n1, n1, n1 * n1,
            X, ld1, ld1 * n1,
            n1, ng1, h1_Tint, h1_total);

        // V1: X -> a1 (Y) + lh1/hl1/hh1
        dwt_v<<<dim3((v1_total + NT - 1) / NT), dim3(NT), 0, stream>>>(
            X, ld1, ld1 * n1, n1,
            m1, m1,
            Y, ld1, a1b,
            lh1 + (size_t)g0 * m1 * m1, hl1 + (size_t)g0 * m1 * m1,
            hh1 + (size_t)g0 * m1 * m1, m1 * m1,
            nfast1, v1_Tint, v1_total);

        // level 2 fused: a1 (Y) -> a2 (X) + lh2/hl2/hh2
        dwt2_fused<<<dim3(t2_ * t2_ * nb), dim3(NTF), 0, stream>>>(
            Y, n2, ld1, a1b,
            m2, t2_, t2_,
            (float*)X, ld2, a2b,
            lh2 + (size_t)g0 * m2 * m2, hl2 + (size_t)g0 * m2 * m2,
            hh2 + (size_t)g0 * m2 * m2);

        // level 3 fused: a2 (X) -> a3 (out) + lh3/hl3/hh3
        dwt2_fused<<<dim3(t3 * t3 * nb), dim3(NTF), 0, stream>>>(
            (float*)X, n3, ld2, a2b,
            m3, t3, t3,
            a3 + (size_t)g0 * m3 * m3, m3, m3 * m3,
            lh3 + (size_t)g0 * m3 * m3, hl3 + (size_t)g0 * m3 * m3,
            hh3 + (size_t)g0 * m3 * m3);
    }
}

// Round 11
// 62.975 us; speedup vs baseline: 1.5938x; 1.1176x over previous
//
#include <hip/hip_runtime.h>

__device__ __forceinline__ int refl(int i, int n) {
    i = (i < 0) ? (-i - 1) : i;
    i = (i >= n) ? (2 * n - 1 - i) : i;
    return i;
}

// RNE bf16 pack: lo -> low16, hi -> high16
__device__ __forceinline__ unsigned bpack(float lo, float hi) {
    union { float f; unsigned u; } a, b;
    a.f = lo; b.f = hi;
    const unsigned ua = (a.u + 0x7FFFu + ((a.u >> 16) & 1u)) >> 16;
    const unsigned ub = (b.u + 0x7FFFu + ((b.u >> 16) & 1u)) & 0xFFFF0000u;
    return ua | ub;
}
__device__ __forceinline__ float b_lo(unsigned u) {
    union { unsigned u; float f; } x; x.u = u << 16; return x.f;
}
__device__ __forceinline__ float b_hi(unsigned u) {
    union { unsigned u; float f; } x; x.u = u & 0xFFFF0000u; return x.f;
}

__device__ __constant__ const float LOF[8] = {
    -0.010597401784997278f,  0.032883011666982945f,
     0.030841381835986965f, -0.18703481171888114f,
    -0.02798376941698385f,   0.6308807679295904f,
     0.7148465705525415f,    0.23037781330885523f };
__device__ __constant__ const float HIF[8] = {
    -0.23037781330885523f,   0.7148465705525415f,
    -0.6308807679295904f,   -0.02798376941698385f,
     0.18703481171888114f,   0.030841381835986965f,
    -0.032883011666982945f, -0.010597401784997278f };

// Phase-A item k for this lane: id = 64k+lane -> halo row tr = id>>3 (0..69),
// group g = id&7 (4 out cols), window cols cw0+8g .. +15.
template<bool FAST>
__device__ __forceinline__ void loadA(int k, int lane,
                                      const float* __restrict__ Ain,
                                      int n, int ldin, int rb, int cw0,
                                      float v[16])
{
    const int id = (k << 6) + lane;
    const int tr = id >> 3, g = id & 7;
    if (FAST) {
        const float* p = Ain + (rb + tr) * ldin + (cw0 + 8 * g);
        const float4 a0 = ((const float4*)p)[0];
        const float4 a1 = ((const float4*)p)[1];
        const float4 a2 = ((const float4*)p)[2];
        const float4 a3 = ((const float4*)p)[3];
        v[0]=a0.x; v[1]=a0.y; v[2]=a0.z; v[3]=a0.w;
        v[4]=a1.x; v[5]=a1.y; v[6]=a1.z; v[7]=a1.w;
        v[8]=a2.x; v[9]=a2.y; v[10]=a2.z; v[11]=a2.w;
        v[12]=a3.x; v[13]=a3.y; v[14]=a3.z; v[15]=a3.w;
    } else {
        const float* row = Ain + refl(rb + tr, n) * ldin;
        const int cb = cw0 + 8 * g;
        #pragma unroll
        for (int u = 0; u < 16; ++u) v[u] = row[refl(cb + u, n)];
    }
}

__device__ __forceinline__ void procA(int k, int lane, unsigned* __restrict__ s,
                                      const float v[16])
{
    const int id = (k << 6) + lane;
    const int tr = id >> 3, g = id & 7;
    unsigned w[4];
    #pragma unroll
    for (int d = 0; d < 4; ++d) {
        float lo = 0.f, hi = 0.f;
        #pragma unroll
        for (int t = 0; t < 8; ++t) {
            const float x = v[2 * d + 9 - t];
            lo += LOF[t] * x;
            hi += HIF[t] * x;
        }
        w[d] = bpack(lo, hi);
    }
    *(uint4*)&s[tr * 36 + 4 * g] = make_uint4(w[0], w[1], w[2], w[3]);
}

// 560 items, 3-deep load pipeline: ~12 dwordx4 outstanding while converting.
template<bool FAST>
__device__ __forceinline__ void phaseA(int lane, const float* __restrict__ Ain,
                                       int n, int ldin, int rb, int cw0,
                                       unsigned* __restrict__ s)
{
    float v0[16], v1[16], v2[16];
    loadA<FAST>(0, lane, Ain, n, ldin, rb, cw0, v0);
    loadA<FAST>(1, lane, Ain, n, ldin, rb, cw0, v1);
    loadA<FAST>(2, lane, Ain, n, ldin, rb, cw0, v2);
    procA(0, lane, s, v0); loadA<FAST>(3, lane, Ain, n, ldin, rb, cw0, v0);
    procA(1, lane, s, v1); loadA<FAST>(4, lane, Ain, n, ldin, rb, cw0, v1);
    procA(2, lane, s, v2); loadA<FAST>(5, lane, Ain, n, ldin, rb, cw0, v2);
    procA(3, lane, s, v0); loadA<FAST>(6, lane, Ain, n, ldin, rb, cw0, v0);
    procA(4, lane, s, v1); loadA<FAST>(7, lane, Ain, n, ldin, rb, cw0, v1);
    procA(5, lane, s, v2);
    if (lane < 48) loadA<FAST>(8, lane, Ain, n, ldin, rb, cw0, v2);
    procA(6, lane, s, v0);
    procA(7, lane, s, v1);
    if (lane < 48) procA(8, lane, s, v2);
}

// One wave = one 32x32 output tile. Single-wave workgroup: NO barrier; each
// wave is an independent latency chain. LDS 70x36 packed bf16 (10,080 B)
// -> 16 blocks/CU. out[i] = sum_k f[k]*x[refl(2i+1-k)], both axes.
__global__ __launch_bounds__(64, 4)
void dwt2_wave(const float* __restrict__ in, int n, int ldin, int inb,
               int m, int nty, int ntx,
               float* __restrict__ oA, int ldA, int Ab,
               float* __restrict__ oH, float* __restrict__ oV,
               float* __restrict__ oD)
{
    __shared__ unsigned s[70 * 36];   // 10080 B

    // bijective XCD-chunked remap, y-fastest tile order (proven R5)
    const int G = gridDim.x;
    const int q = G >> 3, rm = G & 7;
    const int xcd = blockIdx.x & 7, pos = blockIdx.x >> 3;
    const int tile = xcd * q + (xcd < rm ? xcd : rm) + pos;
    const int ty = tile % nty;
    const int t2 = tile / nty;
    const int tx = t2 % ntx;
    const int b  = t2 / ntx;

    const int lane = threadIdx.x;
    const int c0 = tx * 32, r0 = ty * 32;
    const float* Ain = in + b * inb;

    const int rb  = 2 * r0 - 6;    // LDS row t <-> input row rb+t (t 0..69)
    const int cw0 = 2 * c0 - 8;    // group g window: cols cw0+8g .. +15

    const bool interior = (rb >= 0) && (rb + 69 < n) &&
                          (cw0 >= 0) && (cw0 + 71 < n);

    if (interior) phaseA<true >(lane, Ain, n, ldin, rb, cw0, s);
    else          phaseA<false>(lane, Ain, n, ldin, rb, cw0, s);
    // single wave: LDS write->read ordering handled by compiler waitcnt

    // ---- Phase B: lane = col c (0..31) x row-half h; rolling 12-slot window
    const int c = lane & 31, h = lane >> 5;
    const int base = (h << 5) * 36 + c;          // LDS row 32h, col c

    unsigned U[12];
    #pragma unroll
    for (int j = 0; j < 6; ++j) U[j] = s[base + j * 36];

    const int gc = c0 + c;
    const int oaB = b * Ab + gc;
    const int obB = b * m * m + gc;
    const bool cok = (gc < m);

    #pragma unroll
    for (int k = 0; k < 8; ++k) {
        #pragma unroll
        for (int j = 0; j < 4; ++j)
            U[(4 * k + 6 + j) % 12] = s[base + (4 * k + 6 + j) * 36];
        float flo[10], fhi[10];
        #pragma unroll
        for (int j = 0; j < 10; ++j) {
            const unsigned u = U[(4 * k + j) % 12];
            flo[j] = b_lo(u); fhi[j] = b_hi(u);
        }
        float A0 = 0.f, H0 = 0.f, V0 = 0.f, D0 = 0.f;
        float A1 = 0.f, H1 = 0.f, V1 = 0.f, D1 = 0.f;
        #pragma unroll
        for (int t = 0; t < 8; ++t) {
            const float l0 = flo[7 - t], h0 = fhi[7 - t];
            const float l1 = flo[9 - t], h1 = fhi[9 - t];
            A0 += LOF[t] * l0;  H0 += HIF[t] * l0;
            V0 += LOF[t] * h0;  D0 += HIF[t] * h0;
            A1 += LOF[t] * l1;  H1 += HIF[t] * l1;
            V1 += LOF[t] * h1;  D1 += HIF[t] * h1;
        }
        const int pr = (h << 3) + k;
        const int gr = r0 + 2 * pr;
        if (cok) {
            if (gr < m) {
                oA[oaB + gr * ldA] = A0;
                const int od = obB + gr * m;
                oH[od] = H0; oV[od] = V0; oD[od] = D0;
            }
            if (gr + 1 < m) {
                oA[oaB + (gr + 1) * ldA] = A1;
                const int od = obB + (gr + 1) * m;
                oH[od] = H1; oV[od] = V1; oD[od] = D1;
            }
        }
    }
}

extern "C" void kernel_launch(void* const* d_in, const int* in_sizes, int n_in,
                              void* d_out, int out_size, void* d_ws, size_t ws_size,
                              hipStream_t stream) {
    const float* x = (const float*)d_in[0];
    float* out = (float*)d_out;
    float* ws  = (float*)d_ws;

    const int B = 16;
    const int n1 = 1024, m1 = 515;
    const int n2 = 515,  m2 = 261;
    const int n3 = 261,  m3 = 134;

    // padded cA intermediates (rows 16B-aligned)
    const int ld1 = 516, b1 = m1 * ld1;
    const int ld2 = 264, b2 = m2 * ld2;
    float* a1 = ws;
    float* a2 = ws + (size_t)b1 * B;

    const size_t sz1 = (size_t)B * m1 * m1;
    const size_t sz2 = (size_t)B * m2 * m2;
    const size_t sz3 = (size_t)B * m3 * m3;

    // d_out: a3, lh3, hl3, hh3, lh2, hl2, hh2, lh1, hl1, hh1
    float* a3  = out;
    float* lh3 = a3  + sz3;
    float* hl3 = lh3 + sz3;
    float* hh3 = hl3 + sz3;
    float* lh2 = hh3 + sz3;
    float* hl2 = lh2 + sz2;
    float* hh2 = hl2 + sz2;
    float* lh1 = hh2 + sz2;
    float* hl1 = lh1 + sz1;
    float* hh1 = hl1 + sz1;

    const int t1 = (m1 + 31) / 32;   // 17
    const int t2_ = (m2 + 31) / 32;  // 9
    const int t3 = (m3 + 31) / 32;   // 5

    dim3 blk(64);
    dim3 g1(t1 * t1 * B, 1, 1);      // 4624 single-wave blocks
    dim3 g2(t2_ * t2_ * B, 1, 1);    // 1296
    dim3 g3(t3 * t3 * B, 1, 1);      // 400

    dwt2_wave<<<g1, blk, 0, stream>>>(x,  n1, n1, n1 * n1,
                                      m1, t1, t1, a1, ld1, b1, lh1, hl1, hh1);
    dwt2_wave<<<g2, blk, 0, stream>>>(a1, n2, ld1, b1,
                                      m2, t2_, t2_, a2, ld2, b2, lh2, hl2, hh2);
    dwt2_wave<<<g3, blk, 0, stream>>>(a2, n3, ld2, b2,
                                      m3, t3, t3, out, m3, m3 * m3, lh3, hl3, hh3);
}

// Round 12
// 59.586 us; speedup vs baseline: 1.6845x; 1.0569x over previous
//
#include <hip/hip_runtime.h>

__device__ __forceinline__ int refl(int i, int n) {
    i = (i < 0) ? (-i - 1) : i;
    i = (i >= n) ? (2 * n - 1 - i) : i;
    return i;
}

// RNE bf16 pack: lo -> low16, hi -> high16
__device__ __forceinline__ unsigned bpack(float lo, float hi) {
    union { float f; unsigned u; } a, b;
    a.f = lo; b.f = hi;
    const unsigned ua = (a.u + 0x7FFFu + ((a.u >> 16) & 1u)) >> 16;
    const unsigned ub = (b.u + 0x7FFFu + ((b.u >> 16) & 1u)) & 0xFFFF0000u;
    return ua | ub;
}
__device__ __forceinline__ float b_lo(unsigned u) {
    union { unsigned u; float f; } x; x.u = u << 16; return x.f;
}
__device__ __forceinline__ float b_hi(unsigned u) {
    union { unsigned u; float f; } x; x.u = u & 0xFFFF0000u; return x.f;
}

__device__ __constant__ const float LOF[8] = {
    -0.010597401784997278f,  0.032883011666982945f,
     0.030841381835986965f, -0.18703481171888114f,
    -0.02798376941698385f,   0.6308807679295904f,
     0.7148465705525415f,    0.23037781330885523f };
__device__ __constant__ const float HIF[8] = {
    -0.23037781330885523f,   0.7148465705525415f,
    -0.6308807679295904f,   -0.02798376941698385f,
     0.18703481171888114f,   0.030841381835986965f,
    -0.032883011666982945f, -0.010597401784997278f };

// Full-width row-stripe fused 2D DWT level.
// Block = 4 output rows x full width M. Reads 14 complete input rows
// (linear), writes 4 full rows per subband (linear, 256B/store-instr).
// out[i] = sum_k f[k] * x[refl(2i+1-k)], both axes. LDS holds the
// h-transform of the 14 rows, bf16-packed (lo|hi per dword).
template<int N, int LDIN, int M>
__global__ __launch_bounds__(256, 5)
void dwt_stripe(const float* __restrict__ in, int inb,
                float* __restrict__ oA, int ldA, int Ab,
                float* __restrict__ oH, float* __restrict__ oV,
                float* __restrict__ oD)
{
    constexpr int NG  = (M + 7) / 8;    // 8-col groups per row
    constexpr int LDP = 8 * NG;         // LDS pitch (dwords)
    constexpr int S   = (M + 3) / 4;    // stripes per image
    constexpr int NA  = 14 * NG;        // phase-A items
    constexpr int NB  = 2 * LDP;        // phase-B items (2 row-pairs x LDP)

    __shared__ unsigned s[14 * LDP];

    // bijective XCD-chunked remap; stripe order y-fastest within batch so
    // one XCD owns contiguous stripes (halo L2 hits, contiguous writes).
    const int G = gridDim.x;
    const int q = G >> 3, rm = G & 7;
    const int xcd = blockIdx.x & 7, pos = blockIdx.x >> 3;
    const int sid = xcd * q + (xcd < rm ? xcd : rm) + pos;
    const int sy = sid % S, b = sid / S;

    const int tid = threadIdx.x;
    const int gr0 = 4 * sy;
    const int rb  = 2 * gr0 - 6;            // LDS row t <-> input row rb+t
    const float* Ain = in + b * inb;

    // ---- Phase A: h-conv 14 rows -> packed LDS ----
    #pragma unroll
    for (int k = 0; k < (NA + 255) / 256; ++k) {
        const int item = k * 256 + tid;
        if (item < NA) {
            const int trow = item / NG, g = item - trow * NG;
            const int ri = rb + trow;
            const int cb = 16 * g - 8;
            float v[24];
            if (ri >= 0 && ri < N && g >= 1 && 16 * g + 15 < N) {
                const float* p = Ain + ri * LDIN + cb;   // 16B aligned
                #pragma unroll
                for (int j = 0; j < 6; ++j) {
                    const float4 t4 = *(const float4*)(p + 4 * j);
                    v[4*j] = t4.x; v[4*j+1] = t4.y; v[4*j+2] = t4.z; v[4*j+3] = t4.w;
                }
            } else {
                const float* row = Ain + refl(ri, N) * LDIN;
                #pragma unroll
                for (int u = 0; u < 24; ++u) v[u] = row[refl(cb + u, N)];
            }
            unsigned w[8];
            #pragma unroll
            for (int d = 0; d < 8; ++d) {
                float lo = 0.f, hi = 0.f;
                #pragma unroll
                for (int t = 0; t < 8; ++t) {
                    const float x = v[2 * d + 9 - t];
                    lo += LOF[t] * x;
                    hi += HIF[t] * x;
                }
                w[d] = bpack(lo, hi);
            }
            unsigned* dst = &s[trow * LDP + 8 * g];
            *(uint4*)(dst)     = make_uint4(w[0], w[1], w[2], w[3]);
            *(uint4*)(dst + 4) = make_uint4(w[4], w[5], w[6], w[7]);
        }
    }
    __syncthreads();

    // ---- Phase B: v-conv -> 4 subbands, full-row linear stores ----
    #pragma unroll
    for (int k = 0; k < (NB + 255) / 256; ++k) {
        const int item = k * 256 + tid;
        if (item < NB) {
            const int pr = item / LDP, c = item - pr * LDP;
            float lov[10], hiv[10];
            #pragma unroll
            for (int j = 0; j < 10; ++j) {
                const unsigned u = s[(4 * pr + j) * LDP + c];
                lov[j] = b_lo(u); hiv[j] = b_hi(u);
            }
            float A0 = 0.f, H0 = 0.f, V0 = 0.f, D0 = 0.f;
            float A1 = 0.f, H1 = 0.f, V1 = 0.f, D1 = 0.f;
            #pragma unroll
            for (int t = 0; t < 8; ++t) {
                const float l0 = lov[7 - t], h0 = hiv[7 - t];
                const float l1 = lov[9 - t], h1 = hiv[9 - t];
                A0 += LOF[t] * l0;  H0 += HIF[t] * l0;
                V0 += LOF[t] * h0;  D0 += HIF[t] * h0;
                A1 += LOF[t] * l1;  H1 += HIF[t] * l1;
                V1 += LOF[t] * h1;  D1 += HIF[t] * h1;
            }
            const int gr = gr0 + 2 * pr;
            if (c < M) {
                const int od = b * (M * M) + gr * M + c;
                if (gr < M) {
                    oA[b * Ab + gr * ldA + c] = A0;
                    oH[od] = H0; oV[od] = V0; oD[od] = D0;
                }
                if (gr + 1 < M) {
                    oA[b * Ab + (gr + 1) * ldA + c] = A1;
                    oH[od + M] = H1; oV[od + M] = V1; oD[od + M] = D1;
                }
            }
        }
    }
}

extern "C" void kernel_launch(void* const* d_in, const int* in_sizes, int n_in,
                              void* d_out, int out_size, void* d_ws, size_t ws_size,
                              hipStream_t stream) {
    const float* x = (const float*)d_in[0];
    float* out = (float*)d_out;
    float* ws  = (float*)d_ws;

    const int B = 16;
    const int m1 = 515, m2 = 261, m3 = 134;

    // padded cA intermediates (rows 16B-aligned)
    const int ld1 = 516, b1 = m1 * ld1;     // 265740
    const int ld2 = 264, b2 = m2 * ld2;     //  68904
    float* a1 = ws;
    float* a2 = ws + (size_t)b1 * B;

    const size_t sz1 = (size_t)B * m1 * m1;
    const size_t sz2 = (size_t)B * m2 * m2;
    const size_t sz3 = (size_t)B * m3 * m3;

    // d_out: a3, lh3, hl3, hh3, lh2, hl2, hh2, lh1, hl1, hh1
    float* a3  = out;
    float* lh3 = a3  + sz3;
    float* hl3 = lh3 + sz3;
    float* hh3 = hl3 + sz3;
    float* lh2 = hh3 + sz3;
    float* hl2 = lh2 + sz2;
    float* hh2 = hl2 + sz2;
    float* lh1 = hh2 + sz2;
    float* hl1 = lh1 + sz1;
    float* hh1 = hl1 + sz1;

    const int S1 = (m1 + 3) / 4;   // 129
    const int S2 = (m2 + 3) / 4;   // 66
    const int S3 = (m3 + 3) / 4;   // 34

    dim3 blk(256);
    dwt_stripe<1024, 1024, 515><<<dim3(S1 * B), blk, 0, stream>>>(
        x, 1024 * 1024, a1, ld1, b1, lh1, hl1, hh1);
    dwt_stripe<515, 516, 261><<<dim3(S2 * B), blk, 0, stream>>>(
        a1, b1, a2, ld2, b2, lh2, hl2, hh2);
    dwt_stripe<261, 264, 134><<<dim3(S3 * B), blk, 0, stream>>>(
        a2, b2, a3, m3, m3 * m3, lh3, hl3, hh3);
}

// Round 13
// 56.749 us; speedup vs baseline: 1.7687x; 1.0500x over previous
//
#include <hip/hip_runtime.h>

typedef float f4 __attribute__((ext_vector_type(4)));
typedef f4 f4u __attribute__((aligned(4)));   // 4B-aligned float4 store

__device__ __forceinline__ int refl(int i, int n) {
    i = (i < 0) ? (-i - 1) : i;
    i = (i >= n) ? (2 * n - 1 - i) : i;
    return i;
}

__device__ __forceinline__ unsigned bpack(float lo, float hi) {
    union { float f; unsigned u; } a, b;
    a.f = lo; b.f = hi;
    const unsigned ua = (a.u + 0x7FFFu + ((a.u >> 16) & 1u)) >> 16;
    const unsigned ub = (b.u + 0x7FFFu + ((b.u >> 16) & 1u)) & 0xFFFF0000u;
    return ua | ub;
}
__device__ __forceinline__ float b_lo(unsigned u) {
    union { unsigned u; float f; } x; x.u = u << 16; return x.f;
}
__device__ __forceinline__ float b_hi(unsigned u) {
    union { unsigned u; float f; } x; x.u = u & 0xFFFF0000u; return x.f;
}

__device__ __constant__ const float LOF[8] = {
    -0.010597401784997278f,  0.032883011666982945f,
     0.030841381835986965f, -0.18703481171888114f,
    -0.02798376941698385f,   0.6308807679295904f,
     0.7148465705525415f,    0.23037781330885523f };
__device__ __constant__ const float HIF[8] = {
    -0.23037781330885523f,   0.7148465705525415f,
    -0.6308807679295904f,   -0.02798376941698385f,
     0.18703481171888114f,   0.030841381835986965f,
    -0.032883011666982945f, -0.010597401784997278f };

// ---------------- Level-1: full-width 4-row stripes, quad-col stores --------
template<int N, int LDIN, int M>
__global__ __launch_bounds__(256, 3)
void dwt_stripe(const float* __restrict__ in, int inb,
                float* __restrict__ oA, int ldA, int Ab,
                float* __restrict__ oH, float* __restrict__ oV,
                float* __restrict__ oD)
{
    constexpr int NG  = (M + 7) / 8;    // 8-col groups per row
    constexpr int LDP = 8 * NG;         // LDS pitch (dwords)
    constexpr int S   = (M + 3) / 4;    // stripes per image
    constexpr int NA  = 14 * NG;        // phase-A items
    constexpr int NQF = M / 4;          // full col-quads per row
    constexpr int TC  = M - 4 * NQF;    // tail cols
    constexpr int NB  = 2 * NQF + 2 * TC;

    __shared__ unsigned s[14 * LDP];

    const int G = gridDim.x;
    const int q = G >> 3, rm = G & 7;
    const int xcd = blockIdx.x & 7, pos = blockIdx.x >> 3;
    const int sid = xcd * q + (xcd < rm ? xcd : rm) + pos;
    const int sy = sid % S, b = sid / S;

    const int tid = threadIdx.x;
    const int gr0 = 4 * sy;
    const int rb  = 2 * gr0 - 6;
    const float* Ain = in + b * inb;

    // ---- Phase A: h-conv 14 rows -> packed LDS (unchanged from R12) ----
    #pragma unroll
    for (int k = 0; k < (NA + 255) / 256; ++k) {
        const int item = k * 256 + tid;
        if (item < NA) {
            const int trow = item / NG, g = item - trow * NG;
            const int ri = rb + trow;
            const int cb = 16 * g - 8;
            float v[24];
            if (ri >= 0 && ri < N && g >= 1 && 16 * g + 15 < N) {
                const float* p = Ain + ri * LDIN + cb;
                #pragma unroll
                for (int j = 0; j < 6; ++j) {
                    const float4 t4 = *(const float4*)(p + 4 * j);
                    v[4*j] = t4.x; v[4*j+1] = t4.y; v[4*j+2] = t4.z; v[4*j+3] = t4.w;
                }
            } else {
                const float* row = Ain + refl(ri, N) * LDIN;
                #pragma unroll
                for (int u = 0; u < 24; ++u) v[u] = row[refl(cb + u, N)];
            }
            unsigned w[8];
            #pragma unroll
            for (int d = 0; d < 8; ++d) {
                float lo = 0.f, hi = 0.f;
                #pragma unroll
                for (int t = 0; t < 8; ++t) {
                    const float x = v[2 * d + 9 - t];
                    lo += LOF[t] * x;
                    hi += HIF[t] * x;
                }
                w[d] = bpack(lo, hi);
            }
            unsigned* dst = &s[trow * LDP + 8 * g];
            *(uint4*)(dst)     = make_uint4(w[0], w[1], w[2], w[3]);
            *(uint4*)(dst + 4) = make_uint4(w[4], w[5], w[6], w[7]);
        }
    }
    __syncthreads();

    // ---- Phase B: quad-col v-conv -> dwordx4 stores ----
    #pragma unroll
    for (int k = 0; k < (NB + 255) / 256; ++k) {
        const int item = k * 256 + tid;
        if (item < 2 * NQF) {
            const int pr = item / NQF, qc = item - pr * NQF;
            uint4 qv[10];
            #pragma unroll
            for (int j = 0; j < 10; ++j)
                qv[j] = *(const uint4*)&s[(4 * pr + j) * LDP + 4 * qc];

            #pragma unroll
            for (int d = 0; d < 2; ++d) {              // output row gr0+2pr+d
                const int gr = gr0 + 2 * pr + d;
                if (gr >= M) continue;
                f4 vA = 0.f, vH = 0.f, vV = 0.f, vD = 0.f;
                #pragma unroll
                for (int t = 0; t < 8; ++t) {
                    const uint4 qq = qv[2 * d + 7 - t];
                    f4 lo, hi;
                    lo.x = b_lo(qq.x); lo.y = b_lo(qq.y); lo.z = b_lo(qq.z); lo.w = b_lo(qq.w);
                    hi.x = b_hi(qq.x); hi.y = b_hi(qq.y); hi.z = b_hi(qq.z); hi.w = b_hi(qq.w);
                    vA += LOF[t] * lo;  vH += HIF[t] * lo;
                    vV += LOF[t] * hi;  vD += HIF[t] * hi;
                }
                const int cq = 4 * qc;
                *(f4u*)&oA[b * Ab + gr * ldA + cq] = vA;
                const int od = b * (M * M) + gr * M + cq;
                *(f4u*)&oH[od] = vH;
                *(f4u*)&oV[od] = vV;
                *(f4u*)&oD[od] = vD;
            }
        } else if (item < NB) {
            const int e = item - 2 * NQF;
            const int pr = e & 1, c = 4 * NQF + (e >> 1);
            float lov[10], hiv[10];
            #pragma unroll
            for (int j = 0; j < 10; ++j) {
                const unsigned u = s[(4 * pr + j) * LDP + c];
                lov[j] = b_lo(u); hiv[j] = b_hi(u);
            }
            float A0=0.f,H0=0.f,V0=0.f,D0=0.f,A1=0.f,H1=0.f,V1=0.f,D1=0.f;
            #pragma unroll
            for (int t = 0; t < 8; ++t) {
                const float l0 = lov[7 - t], h0 = hiv[7 - t];
                const float l1 = lov[9 - t], h1 = hiv[9 - t];
                A0 += LOF[t] * l0;  H0 += HIF[t] * l0;
                V0 += LOF[t] * h0;  D0 += HIF[t] * h0;
                A1 += LOF[t] * l1;  H1 += HIF[t] * l1;
                V1 += LOF[t] * h1;  D1 += HIF[t] * h1;
            }
            const int gr = gr0 + 2 * pr;
            const int od = b * (M * M) + gr * M + c;
            if (gr < M) {
                oA[b * Ab + gr * ldA + c] = A0;
                oH[od] = H0; oV[od] = V0; oD[od] = D0;
            }
            if (gr + 1 < M) {
                oA[b * Ab + (gr + 1) * ldA + c] = A1;
                oH[od + M] = H1; oV[od + M] = V1; oD[od + M] = D1;
            }
        }
    }
}

// ---------------- Levels 2-3: R8 fused 32x32 tile (proven) ----------------
#define NTF 512
__global__ __launch_bounds__(NTF, 8)
void dwt2_fused(const float* __restrict__ in, int n, int ldin, int inb,
                int m, int nty, int ntx,
                float* __restrict__ oA, int ldA, int Ab,
                float* __restrict__ oH, float* __restrict__ oV,
                float* __restrict__ oD)
{
    __shared__ unsigned s[70 * 36];

    const int G = gridDim.x;
    const int q = G >> 3, rm = G & 7;
    const int xcd = blockIdx.x & 7, pos = blockIdx.x >> 3;
    const int i = xcd * q + (xcd < rm ? xcd : rm) + pos;
    const int ty = i % nty;
    const int t2 = i / nty;
    const int tx = t2 % ntx;
    const int b  = t2 / ntx;

    const int tid = threadIdx.x;
    const int c0 = tx * 32, r0 = ty * 32;
    const float* Ain = in + b * inb;

    const int rb  = 2 * r0 - 6;
    const int cw0 = 2 * c0 - 8;
    const bool interior = (rb >= 0) && (rb + 69 < n) && (cw0 >= 0) && (cw0 + 71 < n);

    const int tr0 = tid >> 3, g0 = tid & 7;
    const bool has2 = (tid < 48);
    const int tr1 = 64 + (tid >> 3), g1 = tid & 7;

    float v0[16], v1[16];
    if (interior) {
        const float* p0 = Ain + (rb + tr0) * ldin + (cw0 + 8 * g0);
        const float4 a0 = ((const float4*)p0)[0];
        const float4 a1 = ((const float4*)p0)[1];
        const float4 a2 = ((const float4*)p0)[2];
        const float4 a3 = ((const float4*)p0)[3];
        v0[0]=a0.x; v0[1]=a0.y; v0[2]=a0.z; v0[3]=a0.w;
        v0[4]=a1.x; v0[5]=a1.y; v0[6]=a1.z; v0[7]=a1.w;
        v0[8]=a2.x; v0[9]=a2.y; v0[10]=a2.z; v0[11]=a2.w;
        v0[12]=a3.x; v0[13]=a3.y; v0[14]=a3.z; v0[15]=a3.w;
        if (has2) {
            const float* p1 = Ain + (rb + tr1) * ldin + (cw0 + 8 * g1);
            const float4 b0 = ((const float4*)p1)[0];
            const float4 b1 = ((const float4*)p1)[1];
            const float4 b2 = ((const float4*)p1)[2];
            const float4 b3 = ((const float4*)p1)[3];
            v1[0]=b0.x; v1[1]=b0.y; v1[2]=b0.z; v1[3]=b0.w;
            v1[4]=b1.x; v1[5]=b1.y; v1[6]=b1.z; v1[7]=b1.w;
            v1[8]=b2.x; v1[9]=b2.y; v1[10]=b2.z; v1[11]=b2.w;
            v1[12]=b3.x; v1[13]=b3.y; v1[14]=b3.z; v1[15]=b3.w;
        }
    } else {
        const float* row0 = Ain + refl(rb + tr0, n) * ldin;
        const int cb0 = cw0 + 8 * g0;
        #pragma unroll
        for (int u = 0; u < 16; ++u) v0[u] = row0[refl(cb0 + u, n)];
        if (has2) {
            const float* row1 = Ain + refl(rb + tr1, n) * ldin;
            const int cb1 = cw0 + 8 * g1;
            #pragma unroll
            for (int u = 0; u < 16; ++u) v1[u] = row1[refl(cb1 + u, n)];
        }
    }

    {
        unsigned w[4];
        #pragma unroll
        for (int d = 0; d < 4; ++d) {
            float lo = 0.f, hi = 0.f;
            #pragma unroll
            for (int t = 0; t < 8; ++t) {
                const float x = v0[2 * d + 9 - t];
                lo += LOF[t] * x;
                hi += HIF[t] * x;
            }
            w[d] = bpack(lo, hi);
        }
        *(uint4*)&s[tr0 * 36 + 4 * g0] = make_uint4(w[0], w[1], w[2], w[3]);
    }
    if (has2) {
        unsigned w[4];
        #pragma unroll
        for (int d = 0; d < 4; ++d) {
            float lo = 0.f, hi = 0.f;
            #pragma unroll
            for (int t = 0; t < 8; ++t) {
                const float x = v1[2 * d + 9 - t];
                lo += LOF[t] * x;
                hi += HIF[t] * x;
            }
            w[d] = bpack(lo, hi);
        }
        *(uint4*)&s[tr1 * 36 + 4 * g1] = make_uint4(w[0], w[1], w[2], w[3]);
    }
    __syncthreads();

    const int c = tid & 31, pr = tid >> 5;
    float lov[10], hiv[10];
    #pragma unroll
    for (int j = 0; j < 10; ++j) {
        const unsigned u = s[(4 * pr + j) * 36 + c];
        lov[j] = b_lo(u); hiv[j] = b_hi(u);
    }
    float A0=0.f,H0=0.f,V0=0.f,D0=0.f,A1=0.f,H1=0.f,V1=0.f,D1=0.f;
    #pragma unroll
    for (int t = 0; t < 8; ++t) {
        const float l0 = lov[7 - t], h0 = hiv[7 - t];
        const float l1 = lov[9 - t], h1 = hiv[9 - t];
        A0 += LOF[t] * l0;  H0 += HIF[t] * l0;
        V0 += LOF[t] * h0;  D0 += HIF[t] * h0;
        A1 += LOF[t] * l1;  H1 += HIF[t] * l1;
        V1 += LOF[t] * h1;  D1 += HIF[t] * h1;
    }
    const int gr = r0 + 2 * pr, gc = c0 + c;
    if (gc < m) {
        const int ob = b * (m * m);
        const int od = ob + gr * m + gc;
        if (gr < m) {
            oA[b * Ab + gr * ldA + gc] = A0;
            oH[od] = H0; oV[od] = V0; oD[od] = D0;
        }
        if (gr + 1 < m) {
            oA[b * Ab + (gr + 1) * ldA + gc] = A1;
            oH[od + m] = H1; oV[od + m] = V1; oD[od + m] = D1;
        }
    }
}

extern "C" void kernel_launch(void* const* d_in, const int* in_sizes, int n_in,
                              void* d_out, int out_size, void* d_ws, size_t ws_size,
                              hipStream_t stream) {
    const float* x = (const float*)d_in[0];
    float* out = (float*)d_out;
    float* ws  = (float*)d_ws;

    const int B = 16;
    const int m1 = 515, m2 = 261, m3 = 134;
    const int n2 = 515, n3 = 261;

    const int ld1 = 516, b1 = m1 * ld1;
    const int ld2 = 264, b2 = m2 * ld2;
    float* a1 = ws;
    float* a2 = ws + (size_t)b1 * B;

    const size_t sz1 = (size_t)B * m1 * m1;
    const size_t sz2 = (size_t)B * m2 * m2;
    const size_t sz3 = (size_t)B * m3 * m3;

    // d_out: a3, lh3, hl3, hh3, lh2, hl2, hh2, lh1, hl1, hh1
    float* a3  = out;
    float* lh3 = a3  + sz3;
    float* hl3 = lh3 + sz3;
    float* hh3 = hl3 + sz3;
    float* lh2 = hh3 + sz3;
    float* hl2 = lh2 + sz2;
    float* hh2 = hl2 + sz2;
    float* lh1 = hh2 + sz2;
    float* hl1 = lh1 + sz1;
    float* hh1 = hl1 + sz1;

    const int S1 = (m1 + 3) / 4;     // 129
    const int t2_ = (m2 + 31) / 32;  // 9
    const int t3  = (m3 + 31) / 32;  // 5

    dim3 blk(256);
    dwt_stripe<1024, 1024, 515><<<dim3(S1 * B), blk, 0, stream>>>(
        x, 1024 * 1024, a1, ld1, b1, lh1, hl1, hh1);

    dwt2_fused<<<dim3(t2_ * t2_ * B), dim3(NTF), 0, stream>>>(
        a1, n2, ld1, b1, m2, t2_, t2_,
        a2, ld2, b2, lh2, hl2, hh2);

    dwt2_fused<<<dim3(t3 * t3 * B), dim3(NTF), 0, stream>>>(
        a2, n3, ld2, b2, m3, t3, t3,
        a3, m3, m3 * m3, lh3, hl3, hh3);
}

// Round 14
// 52.254 us; speedup vs baseline: 1.9208x; 1.0860x over previous
//
#include <hip/hip_runtime.h>

typedef float f4 __attribute__((ext_vector_type(4)));
typedef f4 f4u __attribute__((aligned(4)));   // 4B-aligned float4 store

__device__ __forceinline__ int refl(int i, int n) {
    i = (i < 0) ? (-i - 1) : i;
    i = (i >= n) ? (2 * n - 1 - i) : i;
    return i;
}

__device__ __forceinline__ unsigned bpack(float lo, float hi) {
    union { float f; unsigned u; } a, b;
    a.f = lo; b.f = hi;
    const unsigned ua = (a.u + 0x7FFFu + ((a.u >> 16) & 1u)) >> 16;
    const unsigned ub = (b.u + 0x7FFFu + ((b.u >> 16) & 1u)) & 0xFFFF0000u;
    return ua | ub;
}
__device__ __forceinline__ float b_lo(unsigned u) {
    union { unsigned u; float f; } x; x.u = u << 16; return x.f;
}
__device__ __forceinline__ float b_hi(unsigned u) {
    union { unsigned u; float f; } x; x.u = u & 0xFFFF0000u; return x.f;
}

__device__ __constant__ const float LOF[8] = {
    -0.010597401784997278f,  0.032883011666982945f,
     0.030841381835986965f, -0.18703481171888114f,
    -0.02798376941698385f,   0.6308807679295904f,
     0.7148465705525415f,    0.23037781330885523f };
__device__ __constant__ const float HIF[8] = {
    -0.23037781330885523f,   0.7148465705525415f,
    -0.6308807679295904f,   -0.02798376941698385f,
     0.18703481171888114f,   0.030841381835986965f,
    -0.032883011666982945f, -0.010597401784997278f };

// ------------- Level-1: full-width 8-row stripes, edge-segregated phase A ----
// Block = RPB output rows x full width M. Interior phase-A items (g=1..GHI)
// are branch-free: row reflection is branchless (full-row linear read is
// always valid); only 2 column-edge groups per row take the refl-gather path,
// and they live in a separate index range so interior WAVES never execute it.
template<int N, int LDIN, int M, int RPB>
__global__ __launch_bounds__(256, 3)
void dwt_stripe(const float* __restrict__ in, int inb,
                float* __restrict__ oA, int ldA, int Ab,
                float* __restrict__ oH, float* __restrict__ oV,
                float* __restrict__ oD)
{
    constexpr int NG  = (M + 7) / 8;        // 8-out-col groups per row
    constexpr int LDP = 8 * NG;             // LDS pitch (dwords)
    constexpr int S   = (M + RPB - 1) / RPB;
    constexpr int HR  = 2 * RPB + 6;        // halo rows per stripe
    constexpr int GHI = (N - 16) / 16;      // last branch-free group
    constexpr int NGI = GHI;                // interior groups g = 1..GHI
    static_assert(NG - 1 == GHI + 1, "expect exactly 2 edge groups");
    constexpr int NAI = HR * NGI;           // interior phase-A items
    constexpr int NAT = NAI + HR * 2;       // + edge items
    constexpr int NQF = M / 4;              // full col-quads per row
    constexpr int TC  = M - 4 * NQF;        // tail cols
    constexpr int NBM = (RPB / 2) * NQF;    // main phase-B items
    constexpr int NBT2 = (RPB / 2) * TC;    // tail items
    constexpr int NB  = NBM + NBT2;

    __shared__ unsigned s[HR * LDP];

    const int G = gridDim.x;
    const int q = G >> 3, rm = G & 7;
    const int xcd = blockIdx.x & 7, pos = blockIdx.x >> 3;
    const int sid = xcd * q + (xcd < rm ? xcd : rm) + pos;
    const int sy = sid % S, b = sid / S;

    const int tid = threadIdx.x;
    const int gr0 = RPB * sy;
    const int rb  = 2 * gr0 - 6;            // LDS row t <-> input row rb+t
    const float* Ain = in + b * inb;

    // ---- Phase A ----
    #pragma unroll
    for (int k = 0; k < (NAT + 255) / 256; ++k) {
        const int item = k * 256 + tid;
        if (item < NAI) {
            // interior: branch-free (row refl branchless, cols in-bounds)
            const int tr = item / NGI;
            const int g  = 1 + (item - tr * NGI);
            const int rr = refl(rb + tr, N);
            const float* p = Ain + rr * LDIN + (16 * g - 8);
            float v[24];
            #pragma unroll
            for (int j = 0; j < 6; ++j) {
                const float4 t4 = *(const float4*)(p + 4 * j);
                v[4*j] = t4.x; v[4*j+1] = t4.y; v[4*j+2] = t4.z; v[4*j+3] = t4.w;
            }
            unsigned w[8];
            #pragma unroll
            for (int d = 0; d < 8; ++d) {
                float lo = 0.f, hi = 0.f;
                #pragma unroll
                for (int t = 0; t < 8; ++t) {
                    const float x = v[2 * d + 9 - t];
                    lo += LOF[t] * x;
                    hi += HIF[t] * x;
                }
                w[d] = bpack(lo, hi);
            }
            unsigned* dst = &s[tr * LDP + 8 * g];
            *(uint4*)(dst)     = make_uint4(w[0], w[1], w[2], w[3]);
            *(uint4*)(dst + 4) = make_uint4(w[4], w[5], w[6], w[7]);
        } else if (item < NAT) {
            // column-edge groups g in {0, GHI+1}: refl gather
            const int e  = item - NAI;
            const int tr = e >> 1;
            const int g  = (e & 1) ? (GHI + 1) : 0;
            const int rr = refl(rb + tr, N);
            const float* row = Ain + rr * LDIN;
            const int cb = 16 * g - 8;
            float v[24];
            #pragma unroll
            for (int u = 0; u < 24; ++u) v[u] = row[refl(cb + u, N)];
            unsigned w[8];
            #pragma unroll
            for (int d = 0; d < 8; ++d) {
                float lo = 0.f, hi = 0.f;
                #pragma unroll
                for (int t = 0; t < 8; ++t) {
                    const float x = v[2 * d + 9 - t];
                    lo += LOF[t] * x;
                    hi += HIF[t] * x;
                }
                w[d] = bpack(lo, hi);
            }
            unsigned* dst = &s[tr * LDP + 8 * g];
            *(uint4*)(dst)     = make_uint4(w[0], w[1], w[2], w[3]);
            *(uint4*)(dst + 4) = make_uint4(w[4], w[5], w[6], w[7]);
        }
    }
    __syncthreads();

    // ---- Phase B: quad-col v-conv -> dwordx4 stores ----
    #pragma unroll
    for (int k = 0; k < (NB + 255) / 256; ++k) {
        const int item = k * 256 + tid;
        if (item < NBM) {
            const int pr = item / NQF, qc = item - pr * NQF;
            uint4 qv[10];
            #pragma unroll
            for (int j = 0; j < 10; ++j)
                qv[j] = *(const uint4*)&s[(4 * pr + j) * LDP + 4 * qc];

            #pragma unroll
            for (int d = 0; d < 2; ++d) {
                const int gr = gr0 + 2 * pr + d;
                if (gr >= M) continue;
                f4 vA = 0.f, vH = 0.f, vV = 0.f, vD = 0.f;
                #pragma unroll
                for (int t = 0; t < 8; ++t) {
                    const uint4 qq = qv[2 * d + 7 - t];
                    f4 lo, hi;
                    lo.x = b_lo(qq.x); lo.y = b_lo(qq.y); lo.z = b_lo(qq.z); lo.w = b_lo(qq.w);
                    hi.x = b_hi(qq.x); hi.y = b_hi(qq.y); hi.z = b_hi(qq.z); hi.w = b_hi(qq.w);
                    vA += LOF[t] * lo;  vH += HIF[t] * lo;
                    vV += LOF[t] * hi;  vD += HIF[t] * hi;
                }
                const int cq = 4 * qc;
                *(f4u*)&oA[b * Ab + gr * ldA + cq] = vA;
                const int od = b * (M * M) + gr * M + cq;
                *(f4u*)&oH[od] = vH;
                *(f4u*)&oV[od] = vV;
                *(f4u*)&oD[od] = vD;
            }
        } else if (item < NB) {
            const int e = item - NBM;
            const int pr = e % (RPB / 2), c = 4 * NQF + e / (RPB / 2);
            float lov[10], hiv[10];
            #pragma unroll
            for (int j = 0; j < 10; ++j) {
                const unsigned u = s[(4 * pr + j) * LDP + c];
                lov[j] = b_lo(u); hiv[j] = b_hi(u);
            }
            float A0=0.f,H0=0.f,V0=0.f,D0=0.f,A1=0.f,H1=0.f,V1=0.f,D1=0.f;
            #pragma unroll
            for (int t = 0; t < 8; ++t) {
                const float l0 = lov[7 - t], h0 = hiv[7 - t];
                const float l1 = lov[9 - t], h1 = hiv[9 - t];
                A0 += LOF[t] * l0;  H0 += HIF[t] * l0;
                V0 += LOF[t] * h0;  D0 += HIF[t] * h0;
                A1 += LOF[t] * l1;  H1 += HIF[t] * l1;
                V1 += LOF[t] * h1;  D1 += HIF[t] * h1;
            }
            const int gr = gr0 + 2 * pr;
            const int od = b * (M * M) + gr * M + c;
            if (gr < M) {
                oA[b * Ab + gr * ldA + c] = A0;
                oH[od] = H0; oV[od] = V0; oD[od] = D0;
            }
            if (gr + 1 < M) {
                oA[b * Ab + (gr + 1) * ldA + c] = A1;
                oH[od + M] = H1; oV[od + M] = V1; oD[od + M] = D1;
            }
        }
    }
}

// ---------------- Levels 2-3: R8 fused 32x32 tile (proven) ----------------
#define NTF 512
__global__ __launch_bounds__(NTF, 8)
void dwt2_fused(const float* __restrict__ in, int n, int ldin, int inb,
                int m, int nty, int ntx,
                float* __restrict__ oA, int ldA, int Ab,
                float* __restrict__ oH, float* __restrict__ oV,
                float* __restrict__ oD)
{
    __shared__ unsigned s[70 * 36];

    const int G = gridDim.x;
    const int q = G >> 3, rm = G & 7;
    const int xcd = blockIdx.x & 7, pos = blockIdx.x >> 3;
    const int i = xcd * q + (xcd < rm ? xcd : rm) + pos;
    const int ty = i % nty;
    const int t2 = i / nty;
    const int tx = t2 % ntx;
    const int b  = t2 / ntx;

    const int tid = threadIdx.x;
    const int c0 = tx * 32, r0 = ty * 32;
    const float* Ain = in + b * inb;

    const int rb  = 2 * r0 - 6;
    const int cw0 = 2 * c0 - 8;
    const bool interior = (rb >= 0) && (rb + 69 < n) && (cw0 >= 0) && (cw0 + 71 < n);

    const int tr0 = tid >> 3, g0 = tid & 7;
    const bool has2 = (tid < 48);
    const int tr1 = 64 + (tid >> 3), g1 = tid & 7;

    float v0[16], v1[16];
    if (interior) {
        const float* p0 = Ain + (rb + tr0) * ldin + (cw0 + 8 * g0);
        const float4 a0 = ((const float4*)p0)[0];
        const float4 a1 = ((const float4*)p0)[1];
        const float4 a2 = ((const float4*)p0)[2];
        const float4 a3 = ((const float4*)p0)[3];
        v0[0]=a0.x; v0[1]=a0.y; v0[2]=a0.z; v0[3]=a0.w;
        v0[4]=a1.x; v0[5]=a1.y; v0[6]=a1.z; v0[7]=a1.w;
        v0[8]=a2.x; v0[9]=a2.y; v0[10]=a2.z; v0[11]=a2.w;
        v0[12]=a3.x; v0[13]=a3.y; v0[14]=a3.z; v0[15]=a3.w;
        if (has2) {
            const float* p1 = Ain + (rb + tr1) * ldin + (cw0 + 8 * g1);
            const float4 b0 = ((const float4*)p1)[0];
            const float4 b1 = ((const float4*)p1)[1];
            const float4 b2 = ((const float4*)p1)[2];
            const float4 b3 = ((const float4*)p1)[3];
            v1[0]=b0.x; v1[1]=b0.y; v1[2]=b0.z; v1[3]=b0.w;
            v1[4]=b1.x; v1[5]=b1.y; v1[6]=b1.z; v1[7]=b1.w;
            v1[8]=b2.x; v1[9]=b2.y; v1[10]=b2.z; v1[11]=b2.w;
            v1[12]=b3.x; v1[13]=b3.y; v1[14]=b3.z; v1[15]=b3.w;
        }
    } else {
        const float* row0 = Ain + refl(rb + tr0, n) * ldin;
        const int cb0 = cw0 + 8 * g0;
        #pragma unroll
        for (int u = 0; u < 16; ++u) v0[u] = row0[refl(cb0 + u, n)];
        if (has2) {
            const float* row1 = Ain + refl(rb + tr1, n) * ldin;
            const int cb1 = cw0 + 8 * g1;
            #pragma unroll
            for (int u = 0; u < 16; ++u) v1[u] = row1[refl(cb1 + u, n)];
        }
    }

    {
        unsigned w[4];
        #pragma unroll
        for (int d = 0; d < 4; ++d) {
            float lo = 0.f, hi = 0.f;
            #pragma unroll
            for (int t = 0; t < 8; ++t) {
                const float x = v0[2 * d + 9 - t];
                lo += LOF[t] * x;
                hi += HIF[t] * x;
            }
            w[d] = bpack(lo, hi);
        }
        *(uint4*)&s[tr0 * 36 + 4 * g0] = make_uint4(w[0], w[1], w[2], w[3]);
    }
    if (has2) {
        unsigned w[4];
        #pragma unroll
        for (int d = 0; d < 4; ++d) {
            float lo = 0.f, hi = 0.f;
            #pragma unroll
            for (int t = 0; t < 8; ++t) {
                const float x = v1[2 * d + 9 - t];
                lo += LOF[t] * x;
                hi += HIF[t] * x;
            }
            w[d] = bpack(lo, hi);
        }
        *(uint4*)&s[tr1 * 36 + 4 * g1] = make_uint4(w[0], w[1], w[2], w[3]);
    }
    __syncthreads();

    const int c = tid & 31, pr = tid >> 5;
    float lov[10], hiv[10];
    #pragma unroll
    for (int j = 0; j < 10; ++j) {
        const unsigned u = s[(4 * pr + j) * 36 + c];
        lov[j] = b_lo(u); hiv[j] = b_hi(u);
    }
    float A0=0.f,H0=0.f,V0=0.f,D0=0.f,A1=0.f,H1=0.f,V1=0.f,D1=0.f;
    #pragma unroll
    for (int t = 0; t < 8; ++t) {
        const float l0 = lov[7 - t], h0 = hiv[7 - t];
        const float l1 = lov[9 - t], h1 = hiv[9 - t];
        A0 += LOF[t] * l0;  H0 += HIF[t] * l0;
        V0 += LOF[t] * h0;  D0 += HIF[t] * h0;
        A1 += LOF[t] * l1;  H1 += HIF[t] * l1;
        V1 += LOF[t] * h1;  D1 += HIF[t] * h1;
    }
    const int gr = r0 + 2 * pr, gc = c0 + c;
    if (gc < m) {
        const int ob = b * (m * m);
        const int od = ob + gr * m + gc;
        if (gr < m) {
            oA[b * Ab + gr * ldA + gc] = A0;
            oH[od] = H0; oV[od] = V0; oD[od] = D0;
        }
        if (gr + 1 < m) {
            oA[b * Ab + (gr + 1) * ldA + gc] = A1;
            oH[od + m] = H1; oV[od + m] = V1; oD[od + m] = D1;
        }
    }
}

extern "C" void kernel_launch(void* const* d_in, const int* in_sizes, int n_in,
                              void* d_out, int out_size, void* d_ws, size_t ws_size,
                              hipStream_t stream) {
    const float* x = (const float*)d_in[0];
    float* out = (float*)d_out;
    float* ws  = (float*)d_ws;

    const int B = 16;
    const int m1 = 515, m2 = 261, m3 = 134;
    const int n2 = 515, n3 = 261;

    const int ld1 = 516, b1 = m1 * ld1;
    const int ld2 = 264, b2 = m2 * ld2;
    float* a1 = ws;
    float* a2 = ws + (size_t)b1 * B;

    const size_t sz1 = (size_t)B * m1 * m1;
    const size_t sz2 = (size_t)B * m2 * m2;
    const size_t sz3 = (size_t)B * m3 * m3;

    // d_out: a3, lh3, hl3, hh3, lh2, hl2, hh2, lh1, hl1, hh1
    float* a3  = out;
    float* lh3 = a3  + sz3;
    float* hl3 = lh3 + sz3;
    float* hh3 = hl3 + sz3;
    float* lh2 = hh3 + sz3;
    float* hl2 = lh2 + sz2;
    float* hh2 = hl2 + sz2;
    float* lh1 = hh2 + sz2;
    float* hl1 = lh1 + sz1;
    float* hh1 = hl1 + sz1;

    const int S1 = (m1 + 7) / 8;     // 65 stripes (8 rows each)
    const int t2_ = (m2 + 31) / 32;  // 9
    const int t3  = (m3 + 31) / 32;  // 5

    dim3 blk(256);
    dwt_stripe<1024, 1024, 515, 8><<<dim3(S1 * B), blk, 0, stream>>>(
        x, 1024 * 1024, a1, ld1, b1, lh1, hl1, hh1);

    dwt2_fused<<<dim3(t2_ * t2_ * B), dim3(NTF), 0, stream>>>(
        a1, n2, ld1, b1, m2, t2_, t2_,
        a2, ld2, b2, lh2, hl2, hh2);

    dwt2_fused<<<dim3(t3 * t3 * B), dim3(NTF), 0, stream>>>(
        a2, n3, ld2, b2, m3, t3, t3,
        a3, m3, m3 * m3, lh3, hl3, hh3);
}